// Round 1
// baseline (2867.002 us; speedup 1.0000x reference)
//
#include <hip/hip_runtime.h>
#include <math.h>

#define Bz 32
#define Sz 2048
#define Dz 1024
#define Uz 1024
#define Mz (Bz*Sz)

// ---------------------------------------------------------------------------
// K1: dec_p[b,u] = sum_d h_dec[b,d] * W_dec[d,u] + b_dec[u]
// grid = (Bz*Uz)/256 = 128 blocks; each block = one b, 256 consecutive u
// ---------------------------------------------------------------------------
__global__ __launch_bounds__(256) void dec_proj_kernel(
    const float* __restrict__ h_dec, const float* __restrict__ W_dec,
    const float* __restrict__ b_dec, float* __restrict__ dec_p)
{
    __shared__ float hs[Dz];
    const int b = blockIdx.x >> 2;                    // 4 blocks per b
    const int u = ((blockIdx.x & 3) << 8) + threadIdx.x;
    for (int d = threadIdx.x; d < Dz; d += 256) hs[d] = h_dec[b * Dz + d];
    __syncthreads();
    float acc = 0.f;
#pragma unroll 4
    for (int d = 0; d < Dz; ++d) acc += hs[d] * W_dec[d * Uz + u];
    dec_p[b * Uz + u] = acc + b_dec[u];
}

// ---------------------------------------------------------------------------
// K2 (hot): score[b,s] = sum_u tanh(dec_p[b,u] + h_enc[b,s,:]@W_enc[:,u]) * W_com[u] + b_com
// 64x64 output tile per block, KT=64, 4x4 per-thread micro-tile, fp32 VALU.
// enc_p is never materialized: each 64-wide u-chunk is reduced through
// tanh()*W_com into a running per-row scalar.
// ---------------------------------------------------------------------------
#define MT 64
#define NT 64
#define KT 64

__global__ __launch_bounds__(256) void score_kernel(
    const float* __restrict__ h_enc, const float* __restrict__ W_enc,
    const float* __restrict__ dec_p, const float* __restrict__ W_com,
    const float* __restrict__ b_com, float* __restrict__ score)
{
    // +4 pad keeps float4 LDS reads 16B-aligned and breaks stride-64 banking
    __shared__ __align__(16) float As[KT][MT + 4];   // transposed: As[k][m]
    __shared__ __align__(16) float Bs[KT][NT + 4];   // natural:    Bs[k][n]
    __shared__ float red[MT][17];

    const int tid = threadIdx.x;
    const int tx = tid & 15;          // column group (4 cols each)
    const int ty = tid >> 4;          // row group   (4 rows each)
    const int m0 = blockIdx.x * MT;   // S=2048 % 64 == 0 -> one b per block
    const int b  = m0 / Sz;

    float s_acc = 0.f;                // running score, valid for tid < 64

    for (int u0 = 0; u0 < Uz; u0 += NT) {
        float acc[4][4];
#pragma unroll
        for (int i = 0; i < 4; ++i)
#pragma unroll
            for (int j = 0; j < 4; ++j) acc[i][j] = 0.f;

        for (int k0 = 0; k0 < Dz; k0 += KT) {
            __syncthreads();   // protect LDS from previous tile's readers
            // stage A tile (64 rows x 64 k), transpose into As[k][m]
#pragma unroll
            for (int i = 0; i < 4; ++i) {
                const int row = ty + i * 16;
                const int c4  = tx * 4;
                const float4 v = *(const float4*)&h_enc[(size_t)(m0 + row) * Dz + k0 + c4];
                As[c4 + 0][row] = v.x;
                As[c4 + 1][row] = v.y;
                As[c4 + 2][row] = v.z;
                As[c4 + 3][row] = v.w;
            }
            // stage B tile (64 k x 64 u), natural layout
#pragma unroll
            for (int i = 0; i < 4; ++i) {
                const int row = ty + i * 16;
                const int c4  = tx * 4;
                *(float4*)&Bs[row][c4] =
                    *(const float4*)&W_enc[(size_t)(k0 + row) * Uz + u0 + c4];
            }
            __syncthreads();
#pragma unroll 8
            for (int k = 0; k < KT; ++k) {
                const float4 a = *(const float4*)&As[k][ty * 4];
                const float4 w = *(const float4*)&Bs[k][tx * 4];
                acc[0][0] += a.x * w.x; acc[0][1] += a.x * w.y; acc[0][2] += a.x * w.z; acc[0][3] += a.x * w.w;
                acc[1][0] += a.y * w.x; acc[1][1] += a.y * w.y; acc[1][2] += a.y * w.z; acc[1][3] += a.y * w.w;
                acc[2][0] += a.z * w.x; acc[2][1] += a.z * w.y; acc[2][2] += a.z * w.z; acc[2][3] += a.z * w.w;
                acc[3][0] += a.w * w.x; acc[3][1] += a.w * w.y; acc[3][2] += a.w * w.z; acc[3][3] += a.w * w.w;
            }
        }
        // epilogue for this u-chunk: tanh + dot with W_com, reduce over 64 cols
        const float4 dp = *(const float4*)&dec_p[b * Uz + u0 + tx * 4];
        const float4 wc = *(const float4*)&W_com[u0 + tx * 4];
#pragma unroll
        for (int i = 0; i < 4; ++i) {
            const float p = tanhf(acc[i][0] + dp.x) * wc.x
                          + tanhf(acc[i][1] + dp.y) * wc.y
                          + tanhf(acc[i][2] + dp.z) * wc.z
                          + tanhf(acc[i][3] + dp.w) * wc.w;
            red[ty * 4 + i][tx] = p;
        }
        __syncthreads();
        if (tid < MT) {
            float t = 0.f;
#pragma unroll
            for (int j = 0; j < 16; ++j) t += red[tid][j];
            s_acc += t;
        }
        // red reuse is protected by the k0-loop barriers of the next chunk
    }
    if (tid < MT) score[m0 + tid] = s_acc + b_com[0];
}

// ---------------------------------------------------------------------------
// K3: softmax over S per b; writes attn straight into d_out's second region
// ---------------------------------------------------------------------------
__global__ __launch_bounds__(256) void softmax_kernel(
    const float* __restrict__ score, float* __restrict__ attn)
{
    __shared__ float red[256];
    const int b = blockIdx.x;
    const int tid = threadIdx.x;
    const float* srow = score + b * Sz;

    float v[8];
    float lm = -1e30f;
#pragma unroll
    for (int i = 0; i < 8; ++i) {
        v[i] = srow[i * 256 + tid];
        lm = fmaxf(lm, v[i]);
    }
    red[tid] = lm; __syncthreads();
    for (int off = 128; off > 0; off >>= 1) {
        if (tid < off) red[tid] = fmaxf(red[tid], red[tid + off]);
        __syncthreads();
    }
    const float mx = red[0];
    __syncthreads();

    float ls = 0.f;
#pragma unroll
    for (int i = 0; i < 8; ++i) { v[i] = expf(v[i] - mx); ls += v[i]; }
    red[tid] = ls; __syncthreads();
    for (int off = 128; off > 0; off >>= 1) {
        if (tid < off) red[tid] += red[tid + off];
        __syncthreads();
    }
    const float inv = 1.f / red[0];
#pragma unroll
    for (int i = 0; i < 8; ++i) attn[b * Sz + i * 256 + tid] = v[i] * inv;
}

// ---------------------------------------------------------------------------
// K4: wsum[b,d] = sum_s attn[b,s] * h_enc[b,s,d]   (memory-bound, 268 MB read)
// grid = Bz*16; each block does 128 s-rows, all 1024 d via float4/thread
// ---------------------------------------------------------------------------
__global__ __launch_bounds__(256) void wsum_kernel(
    const float* __restrict__ h_enc, const float* __restrict__ attn,
    float* __restrict__ wsum)
{
    __shared__ float aw[128];
    const int b  = blockIdx.x >> 4;
    const int s0 = (blockIdx.x & 15) * 128;
    const int tid = threadIdx.x;
    if (tid < 128) aw[tid] = attn[b * Sz + s0 + tid];
    __syncthreads();

    float4 acc = {0.f, 0.f, 0.f, 0.f};
    const float* base = h_enc + ((size_t)b * Sz + s0) * Dz + tid * 4;
#pragma unroll 2
    for (int s = 0; s < 128; ++s) {
        const float a = aw[s];
        const float4 h = *(const float4*)(base + (size_t)s * Dz);
        acc.x += a * h.x; acc.y += a * h.y; acc.z += a * h.z; acc.w += a * h.w;
    }
    float* o = wsum + b * Dz + tid * 4;
    atomicAdd(o + 0, acc.x);
    atomicAdd(o + 1, acc.y);
    atomicAdd(o + 2, acc.z);
    atomicAdd(o + 3, acc.w);
}

// ---------------------------------------------------------------------------
// K5: context[b,u] = sum_d wsum[b,d] * W_enc[d,u] + b_enc[u]
// ---------------------------------------------------------------------------
__global__ __launch_bounds__(256) void ctx_kernel(
    const float* __restrict__ wsum, const float* __restrict__ W_enc,
    const float* __restrict__ b_enc, float* __restrict__ out)
{
    __shared__ float hs[Dz];
    const int b = blockIdx.x >> 2;
    const int u = ((blockIdx.x & 3) << 8) + threadIdx.x;
    for (int d = threadIdx.x; d < Dz; d += 256) hs[d] = wsum[b * Dz + d];
    __syncthreads();
    float acc = 0.f;
#pragma unroll 4
    for (int d = 0; d < Dz; ++d) acc += hs[d] * W_enc[d * Uz + u];
    out[b * Uz + u] = acc + b_enc[u];
}

// ---------------------------------------------------------------------------
extern "C" void kernel_launch(void* const* d_in, const int* in_sizes, int n_in,
                              void* d_out, int out_size, void* d_ws, size_t ws_size,
                              hipStream_t stream)
{
    const float* h_enc = (const float*)d_in[0];
    const float* h_dec = (const float*)d_in[1];
    const float* W_enc = (const float*)d_in[2];
    const float* b_enc = (const float*)d_in[3];
    const float* W_dec = (const float*)d_in[4];
    const float* b_dec = (const float*)d_in[5];
    const float* W_com = (const float*)d_in[6];
    const float* b_com = (const float*)d_in[7];

    float* out_ctx  = (float*)d_out;            // [B,U] = 32768
    float* out_attn = out_ctx + Bz * Uz;        // [B,S] = 65536

    float* ws    = (float*)d_ws;                // total scratch: 512 KB
    float* dec_p = ws;                          // B*U  = 32768 floats
    float* score = ws + Bz * Uz;                // B*S  = 65536 floats
    float* wsum  = ws + Bz * Uz + Bz * Sz;      // B*D  = 32768 floats

    dec_proj_kernel<<<(Bz * Uz) / 256, 256, 0, stream>>>(h_dec, W_dec, b_dec, dec_p);
    score_kernel<<<Mz / MT, 256, 0, stream>>>(h_enc, W_enc, dec_p, W_com, b_com, score);
    softmax_kernel<<<Bz, 256, 0, stream>>>(score, out_attn);
    hipMemsetAsync(wsum, 0, Bz * Dz * sizeof(float), stream);
    wsum_kernel<<<Bz * 16, 256, 0, stream>>>(h_enc, out_attn, wsum);
    ctx_kernel<<<(Bz * Uz) / 256, 256, 0, stream>>>(wsum, W_enc, b_enc, out_ctx);
}

// Round 2
// 962.136 us; speedup vs baseline: 2.9798x; 2.9798x over previous
//
#include <hip/hip_runtime.h>
#include <math.h>
#include <stdint.h>

#define Bz 32
#define Sz 2048
#define Dz 1024
#define Uz 1024
#define Mz (Bz*Sz)

typedef __attribute__((ext_vector_type(8))) short bf16x8;
typedef __attribute__((ext_vector_type(4))) float f32x4;

__device__ __forceinline__ unsigned short f2bf(float f) {
    union { float f; uint32_t u; } v; v.f = f;
    uint32_t r = v.u + 0x7FFFu + ((v.u >> 16) & 1u);   // RNE
    return (unsigned short)(r >> 16);
}

__device__ __forceinline__ float fast_tanh(float x) {
    // 1 - 2/(e^{2x}+1); exact at +/-inf, ~1e-5 rel err — far below bf16 noise
    float e = __expf(2.f * x);
    return 1.f - 2.f * __builtin_amdgcn_rcpf(e + 1.f);
}

// async global->LDS, 16B per lane; LDS dest = wave-uniform base + lane*16
#define GLD16(gsrc, ldst) \
    __builtin_amdgcn_global_load_lds((__attribute__((address_space(1))) void*)(void*)(gsrc), \
        (__attribute__((address_space(3))) void*)(ldst), 16, 0, 0)

// ---------------------------------------------------------------------------
// h_enc fp32 [Mz][Dz] -> bf16, same layout. 8 elems/thread.
// ---------------------------------------------------------------------------
__global__ __launch_bounds__(256) void conv_h_kernel(
    const float* __restrict__ in, unsigned short* __restrict__ out)
{
    const size_t i = ((size_t)blockIdx.x * 256 + threadIdx.x) * 8;
    const float4 a = *(const float4*)(in + i);
    const float4 c = *(const float4*)(in + i + 4);
    union { unsigned short s[8]; uint4 v; } o;
    o.s[0] = f2bf(a.x); o.s[1] = f2bf(a.y); o.s[2] = f2bf(a.z); o.s[3] = f2bf(a.w);
    o.s[4] = f2bf(c.x); o.s[5] = f2bf(c.y); o.s[6] = f2bf(c.z); o.s[7] = f2bf(c.w);
    *(uint4*)(out + i) = o.v;
}

// ---------------------------------------------------------------------------
// W_enc fp32 [Dz][Uz] -> wT bf16 [Uz][Dz] (transposed so k is contiguous)
// 64x64 tiles via LDS, conflict-free (65-float stride)
// ---------------------------------------------------------------------------
__global__ __launch_bounds__(256) void wT_kernel(
    const float* __restrict__ W, unsigned short* __restrict__ wT)
{
    __shared__ float tile[64][65];
    const int t  = threadIdx.x;
    const int c  = t & 63;
    const int r0 = t >> 6;                       // 0..3
    const int u0 = (blockIdx.x & 15) * 64;
    const int d0 = (blockIdx.x >> 4) * 64;
    for (int r = r0; r < 64; r += 4)
        tile[r][c] = W[(size_t)(d0 + r) * Uz + u0 + c];
    __syncthreads();
    for (int r = r0; r < 64; r += 4)
        wT[(size_t)(u0 + r) * Dz + d0 + c] = f2bf(tile[c][r]);
}

// ---------------------------------------------------------------------------
// K1: dec_p[b,u] = h_dec[b,:] @ W_dec[:,u] + b_dec[u]  (fp32, tiny)
// ---------------------------------------------------------------------------
__global__ __launch_bounds__(256) void dec_proj_kernel(
    const float* __restrict__ h_dec, const float* __restrict__ W_dec,
    const float* __restrict__ b_dec, float* __restrict__ dec_p)
{
    __shared__ float hs[Dz];
    const int b = blockIdx.x >> 2;
    const int u = ((blockIdx.x & 3) << 8) + threadIdx.x;
    for (int d = threadIdx.x; d < Dz; d += 256) hs[d] = h_dec[b * Dz + d];
    __syncthreads();
    float acc = 0.f;
#pragma unroll 4
    for (int d = 0; d < Dz; ++d) acc += hs[d] * W_dec[d * Uz + u];
    dec_p[b * Uz + u] = acc + b_dec[u];
}

// ---------------------------------------------------------------------------
// K2 (hot, MFMA): score[b,s] = sum_u tanh(dec_p + h_enc@W_enc) * W_com + b_com
// 128x128 tile / block, BK=32, 4 waves, each wave 4x4 grid of 16x16x32 MFMA.
// LDS is fragment-linear: [group g][lane][8 bf16] so global_load_lds's
// (base + lane*16) mapping IS the fragment layout; ds_read_b128 at
// base+lane*16 is conflict-free. enc_p never materialized.
// ---------------------------------------------------------------------------
__global__ __launch_bounds__(256) void score_mfma_kernel(
    const unsigned short* __restrict__ hbf,   // [Mz][Dz] bf16
    const unsigned short* __restrict__ wT,    // [Uz][Dz] bf16
    const float* __restrict__ dec_p,
    const float* __restrict__ W_com,
    const float* __restrict__ b_com,
    float* __restrict__ score)
{
    __shared__ unsigned short As[8 * 512];    // 8 m-groups x 64 lanes x 8 bf16 = 8KB
    __shared__ unsigned short Bs[8 * 512];    // 8 n-groups
    __shared__ float srow[128][2];

    const int tid  = threadIdx.x;
    const int w    = tid >> 6;
    const int lane = tid & 63;
    const int ln   = lane & 15;
    const int q    = lane >> 4;
    const int wm   = w & 1;                   // wave row-half
    const int wn   = w >> 1;                  // wave col-half
    const int m0   = blockIdx.x * 128;        // 2048 % 128 == 0 -> single b
    const int b    = m0 / Sz;

    if (tid < 128) { srow[tid][0] = 0.f; srow[tid][1] = 0.f; }

    const int g0 = 2 * w;                     // this wave stages groups g0, g0+1
    // A: row = m0 + g*16 + ln, col = k0 + q*8 (bf16, k-contiguous)
    const unsigned short* agp0 = hbf + (size_t)(m0 + g0 * 16 + ln) * Dz + q * 8;
    const unsigned short* agp1 = agp0 + (size_t)16 * Dz;
    unsigned short* alp0 = As + g0 * 512;     // wave-uniform LDS base
    unsigned short* alp1 = alp0 + 512;

    for (int u0 = 0; u0 < Uz; u0 += 128) {
        f32x4 acc[4][4];
#pragma unroll
        for (int i = 0; i < 4; ++i)
#pragma unroll
            for (int j = 0; j < 4; ++j) acc[i][j] = (f32x4){0.f, 0.f, 0.f, 0.f};

        const unsigned short* bgp0 = wT + (size_t)(u0 + g0 * 16 + ln) * Dz + q * 8;
        const unsigned short* bgp1 = bgp0 + (size_t)16 * Dz;
        unsigned short* blp0 = Bs + g0 * 512;
        unsigned short* blp1 = blp0 + 512;

        for (int k0 = 0; k0 < Dz; k0 += 32) {
            __syncthreads();                  // protect LDS from prev readers
            GLD16(agp0 + k0, alp0);
            GLD16(agp1 + k0, alp1);
            GLD16(bgp0 + k0, blp0);
            GLD16(bgp1 + k0, blp1);
            __syncthreads();                  // drains vmcnt before barrier

            bf16x8 af[4], bfr[4];
#pragma unroll
            for (int i = 0; i < 4; ++i)
                af[i] = *(const bf16x8*)(As + (wm * 4 + i) * 512 + lane * 8);
#pragma unroll
            for (int j = 0; j < 4; ++j)
                bfr[j] = *(const bf16x8*)(Bs + (wn * 4 + j) * 512 + lane * 8);
#pragma unroll
            for (int i = 0; i < 4; ++i)
#pragma unroll
                for (int j = 0; j < 4; ++j)
                    acc[i][j] = __builtin_amdgcn_mfma_f32_16x16x32_bf16(
                        af[i], bfr[j], acc[i][j], 0, 0, 0);
        }

        // epilogue: tanh + dot(W_com) for this 128-wide u-chunk
        float dpv[4], wcv[4];
#pragma unroll
        for (int j = 0; j < 4; ++j) {
            const int u = u0 + wn * 64 + j * 16 + ln;
            dpv[j] = dec_p[b * Uz + u];
            wcv[j] = W_com[u];
        }
#pragma unroll
        for (int i = 0; i < 4; ++i) {
            float rs[4];
#pragma unroll
            for (int r = 0; r < 4; ++r) {
                float v = 0.f;
#pragma unroll
                for (int j = 0; j < 4; ++j)
                    v += fast_tanh(acc[i][j][r] + dpv[j]) * wcv[j];
                rs[r] = v;
            }
#pragma unroll
            for (int off = 1; off < 16; off <<= 1) {
#pragma unroll
                for (int r = 0; r < 4; ++r) rs[r] += __shfl_xor(rs[r], off, 64);
            }
            if (ln == 0) {
                const int row = wm * 64 + i * 16 + q * 4;  // D: row=(lane>>4)*4+r
#pragma unroll
                for (int r = 0; r < 4; ++r) srow[row + r][wn] += rs[r];
            }
        }
    }
    __syncthreads();
    if (tid < 128) score[m0 + tid] = srow[tid][0] + srow[tid][1] + b_com[0];
}

// ---------------------------------------------------------------------------
// K2-fallback (fp32 VALU) — used only if ws is too small for bf16 staging
// ---------------------------------------------------------------------------
#define MT 64
#define NT 64
#define KT 64
__global__ __launch_bounds__(256) void score_kernel(
    const float* __restrict__ h_enc, const float* __restrict__ W_enc,
    const float* __restrict__ dec_p, const float* __restrict__ W_com,
    const float* __restrict__ b_com, float* __restrict__ score)
{
    __shared__ __align__(16) float As[KT][MT + 4];
    __shared__ __align__(16) float Bs[KT][NT + 4];
    __shared__ float red[MT][17];
    const int tid = threadIdx.x;
    const int tx = tid & 15;
    const int ty = tid >> 4;
    const int m0 = blockIdx.x * MT;
    const int b  = m0 / Sz;
    float s_acc = 0.f;
    for (int u0 = 0; u0 < Uz; u0 += NT) {
        float acc[4][4];
#pragma unroll
        for (int i = 0; i < 4; ++i)
#pragma unroll
            for (int j = 0; j < 4; ++j) acc[i][j] = 0.f;
        for (int k0 = 0; k0 < Dz; k0 += KT) {
            __syncthreads();
#pragma unroll
            for (int i = 0; i < 4; ++i) {
                const int row = ty + i * 16;
                const int c4  = tx * 4;
                const float4 v = *(const float4*)&h_enc[(size_t)(m0 + row) * Dz + k0 + c4];
                As[c4 + 0][row] = v.x; As[c4 + 1][row] = v.y;
                As[c4 + 2][row] = v.z; As[c4 + 3][row] = v.w;
            }
#pragma unroll
            for (int i = 0; i < 4; ++i) {
                const int row = ty + i * 16;
                *(float4*)&Bs[row][tx * 4] =
                    *(const float4*)&W_enc[(size_t)(k0 + row) * Uz + u0 + tx * 4];
            }
            __syncthreads();
#pragma unroll 8
            for (int k = 0; k < KT; ++k) {
                const float4 a = *(const float4*)&As[k][ty * 4];
                const float4 wv = *(const float4*)&Bs[k][tx * 4];
                acc[0][0] += a.x * wv.x; acc[0][1] += a.x * wv.y; acc[0][2] += a.x * wv.z; acc[0][3] += a.x * wv.w;
                acc[1][0] += a.y * wv.x; acc[1][1] += a.y * wv.y; acc[1][2] += a.y * wv.z; acc[1][3] += a.y * wv.w;
                acc[2][0] += a.z * wv.x; acc[2][1] += a.z * wv.y; acc[2][2] += a.z * wv.z; acc[2][3] += a.z * wv.w;
                acc[3][0] += a.w * wv.x; acc[3][1] += a.w * wv.y; acc[3][2] += a.w * wv.z; acc[3][3] += a.w * wv.w;
            }
        }
        const float4 dp = *(const float4*)&dec_p[b * Uz + u0 + tx * 4];
        const float4 wc = *(const float4*)&W_com[u0 + tx * 4];
#pragma unroll
        for (int i = 0; i < 4; ++i) {
            const float p = tanhf(acc[i][0] + dp.x) * wc.x + tanhf(acc[i][1] + dp.y) * wc.y
                          + tanhf(acc[i][2] + dp.z) * wc.z + tanhf(acc[i][3] + dp.w) * wc.w;
            red[ty * 4 + i][tx] = p;
        }
        __syncthreads();
        if (tid < MT) {
            float t = 0.f;
#pragma unroll
            for (int j = 0; j < 16; ++j) t += red[tid][j];
            s_acc += t;
        }
    }
    if (tid < MT) score[m0 + tid] = s_acc + b_com[0];
}

// ---------------------------------------------------------------------------
// K3: softmax over S per b -> attn (second output region)
// ---------------------------------------------------------------------------
__global__ __launch_bounds__(256) void softmax_kernel(
    const float* __restrict__ score, float* __restrict__ attn)
{
    __shared__ float red[256];
    const int b = blockIdx.x;
    const int tid = threadIdx.x;
    const float* srow = score + b * Sz;
    float v[8];
    float lm = -1e30f;
#pragma unroll
    for (int i = 0; i < 8; ++i) { v[i] = srow[i * 256 + tid]; lm = fmaxf(lm, v[i]); }
    red[tid] = lm; __syncthreads();
    for (int off = 128; off > 0; off >>= 1) {
        if (tid < off) red[tid] = fmaxf(red[tid], red[tid + off]);
        __syncthreads();
    }
    const float mx = red[0];
    __syncthreads();
    float ls = 0.f;
#pragma unroll
    for (int i = 0; i < 8; ++i) { v[i] = expf(v[i] - mx); ls += v[i]; }
    red[tid] = ls; __syncthreads();
    for (int off = 128; off > 0; off >>= 1) {
        if (tid < off) red[tid] += red[tid + off];
        __syncthreads();
    }
    const float inv = 1.f / red[0];
#pragma unroll
    for (int i = 0; i < 8; ++i) attn[b * Sz + i * 256 + tid] = v[i] * inv;
}

// ---------------------------------------------------------------------------
// K4: wsum[b,d] = sum_s attn[b,s] * h_enc[b,s,d]  (fp32, memory-bound)
// ---------------------------------------------------------------------------
__global__ __launch_bounds__(256) void wsum_kernel(
    const float* __restrict__ h_enc, const float* __restrict__ attn,
    float* __restrict__ wsum)
{
    __shared__ float aw[128];
    const int b  = blockIdx.x >> 4;
    const int s0 = (blockIdx.x & 15) * 128;
    const int tid = threadIdx.x;
    if (tid < 128) aw[tid] = attn[b * Sz + s0 + tid];
    __syncthreads();
    float4 acc = {0.f, 0.f, 0.f, 0.f};
    const float* base = h_enc + ((size_t)b * Sz + s0) * Dz + tid * 4;
#pragma unroll 2
    for (int s = 0; s < 128; ++s) {
        const float a = aw[s];
        const float4 h = *(const float4*)(base + (size_t)s * Dz);
        acc.x += a * h.x; acc.y += a * h.y; acc.z += a * h.z; acc.w += a * h.w;
    }
    float* o = wsum + b * Dz + tid * 4;
    atomicAdd(o + 0, acc.x); atomicAdd(o + 1, acc.y);
    atomicAdd(o + 2, acc.z); atomicAdd(o + 3, acc.w);
}

// ---------------------------------------------------------------------------
// K5: context[b,u] = wsum[b,:] @ W_enc[:,u] + b_enc[u]
// ---------------------------------------------------------------------------
__global__ __launch_bounds__(256) void ctx_kernel(
    const float* __restrict__ wsum, const float* __restrict__ W_enc,
    const float* __restrict__ b_enc, float* __restrict__ out)
{
    __shared__ float hs[Dz];
    const int b = blockIdx.x >> 2;
    const int u = ((blockIdx.x & 3) << 8) + threadIdx.x;
    for (int d = threadIdx.x; d < Dz; d += 256) hs[d] = wsum[b * Dz + d];
    __syncthreads();
    float acc = 0.f;
#pragma unroll 4
    for (int d = 0; d < Dz; ++d) acc += hs[d] * W_enc[d * Uz + u];
    out[b * Uz + u] = acc + b_enc[u];
}

// ---------------------------------------------------------------------------
extern "C" void kernel_launch(void* const* d_in, const int* in_sizes, int n_in,
                              void* d_out, int out_size, void* d_ws, size_t ws_size,
                              hipStream_t stream)
{
    const float* h_enc = (const float*)d_in[0];
    const float* h_dec = (const float*)d_in[1];
    const float* W_enc = (const float*)d_in[2];
    const float* b_enc = (const float*)d_in[3];
    const float* W_dec = (const float*)d_in[4];
    const float* b_dec = (const float*)d_in[5];
    const float* W_com = (const float*)d_in[6];
    const float* b_com = (const float*)d_in[7];

    float* out_ctx  = (float*)d_out;            // [B,U]
    float* out_attn = out_ctx + Bz * Uz;        // [B,S]

    const size_t HBF_BYTES = (size_t)Mz * Dz * 2;       // 128 MiB
    const size_t WT_BYTES  = (size_t)Uz * Dz * 2;       // 2 MiB
    const size_t SMALL     = (size_t)(Bz*Uz + Bz*Sz + Bz*Dz) * 4;
    const size_t need      = HBF_BYTES + WT_BYTES + SMALL;

    if (ws_size >= need) {
        char* wsb = (char*)d_ws;
        unsigned short* hbf = (unsigned short*)wsb;
        unsigned short* wT  = (unsigned short*)(wsb + HBF_BYTES);
        float* dec_p = (float*)(wsb + HBF_BYTES + WT_BYTES);
        float* score = dec_p + Bz * Uz;
        float* wsum  = score + Bz * Sz;

        conv_h_kernel<<<(Mz * Dz) / (256 * 8), 256, 0, stream>>>(h_enc, hbf);
        wT_kernel<<<256, 256, 0, stream>>>(W_enc, wT);
        dec_proj_kernel<<<(Bz * Uz) / 256, 256, 0, stream>>>(h_dec, W_dec, b_dec, dec_p);
        score_mfma_kernel<<<Mz / 128, 256, 0, stream>>>(hbf, wT, dec_p, W_com, b_com, score);
        softmax_kernel<<<Bz, 256, 0, stream>>>(score, out_attn);
        hipMemsetAsync(wsum, 0, Bz * Dz * sizeof(float), stream);
        wsum_kernel<<<Bz * 16, 256, 0, stream>>>(h_enc, out_attn, wsum);
        ctx_kernel<<<(Bz * Uz) / 256, 256, 0, stream>>>(wsum, W_enc, b_enc, out_ctx);
    } else {
        float* ws    = (float*)d_ws;
        float* dec_p = ws;
        float* score = ws + Bz * Uz;
        float* wsum  = ws + Bz * Uz + Bz * Sz;

        dec_proj_kernel<<<(Bz * Uz) / 256, 256, 0, stream>>>(h_dec, W_dec, b_dec, dec_p);
        score_kernel<<<Mz / MT, 256, 0, stream>>>(h_enc, W_enc, dec_p, W_com, b_com, score);
        softmax_kernel<<<Bz, 256, 0, stream>>>(score, out_attn);
        hipMemsetAsync(wsum, 0, Bz * Dz * sizeof(float), stream);
        wsum_kernel<<<Bz * 16, 256, 0, stream>>>(h_enc, out_attn, wsum);
        ctx_kernel<<<(Bz * Uz) / 256, 256, 0, stream>>>(wsum, W_enc, b_enc, out_ctx);
    }
}

// Round 3
// 863.151 us; speedup vs baseline: 3.3216x; 1.1147x over previous
//
#include <hip/hip_runtime.h>
#include <math.h>
#include <stdint.h>

#define Bz 32
#define Sz 2048
#define Dz 1024
#define Uz 1024
#define Mz (Bz*Sz)

typedef __attribute__((ext_vector_type(8))) short bf16x8;
typedef __attribute__((ext_vector_type(4))) float f32x4;

__device__ __forceinline__ unsigned short f2bf(float f) {
    union { float f; uint32_t u; } v; v.f = f;
    uint32_t r = v.u + 0x7FFFu + ((v.u >> 16) & 1u);   // RNE
    return (unsigned short)(r >> 16);
}

__device__ __forceinline__ float fast_tanh(float x) {
    float e = __expf(2.f * x);
    return 1.f - 2.f * __builtin_amdgcn_rcpf(e + 1.f);
}

#define GLD16(gsrc, ldst) \
    __builtin_amdgcn_global_load_lds((__attribute__((address_space(1))) void*)(void*)(gsrc), \
        (__attribute__((address_space(3))) void*)(ldst), 16, 0, 0)

#define CONV_BLOCKS 32768   // (Mz*Dz)/(256*8)
#define WT_BLOCKS   256
#define DECI_BLOCKS 32

// ---------------------------------------------------------------------------
// PREP (fused): [0,32768) h_enc->bf16 | [32768,33024) W_enc->wT bf16 |
//               [33024,33056) dec_p init = b_dec
// ---------------------------------------------------------------------------
__global__ __launch_bounds__(256) void prep_kernel(
    const float* __restrict__ h_enc, unsigned short* __restrict__ hbf,
    const float* __restrict__ W_enc, unsigned short* __restrict__ wT,
    const float* __restrict__ b_dec, float* __restrict__ dec_p)
{
    __shared__ float tile[64][65];
    const int bid = blockIdx.x;
    const int tid = threadIdx.x;
    if (bid < CONV_BLOCKS) {
        const size_t i = ((size_t)bid * 256 + tid) * 8;
        const float4 a = *(const float4*)(h_enc + i);
        const float4 c = *(const float4*)(h_enc + i + 4);
        union { unsigned short s[8]; uint4 v; } o;
        o.s[0] = f2bf(a.x); o.s[1] = f2bf(a.y); o.s[2] = f2bf(a.z); o.s[3] = f2bf(a.w);
        o.s[4] = f2bf(c.x); o.s[5] = f2bf(c.y); o.s[6] = f2bf(c.z); o.s[7] = f2bf(c.w);
        *(uint4*)(hbf + i) = o.v;
    } else if (bid < CONV_BLOCKS + WT_BLOCKS) {
        const int b2 = bid - CONV_BLOCKS;
        const int c  = tid & 63;
        const int r0 = tid >> 6;
        const int u0 = (b2 & 15) * 64;
        const int d0 = (b2 >> 4) * 64;
        for (int r = r0; r < 64; r += 4)
            tile[r][c] = W_enc[(size_t)(d0 + r) * Uz + u0 + c];
        __syncthreads();
        for (int r = r0; r < 64; r += 4)
            wT[(size_t)(u0 + r) * Dz + d0 + c] = f2bf(tile[c][r]);
    } else {
        const int b3 = bid - (CONV_BLOCKS + WT_BLOCKS);
        const int u4 = tid * 4;
        *(float4*)&dec_p[b3 * Uz + u4] = *(const float4*)&b_dec[u4];
    }
}

// ---------------------------------------------------------------------------
// dec_p[b,u] += sum over d-chunk of h_dec[b,d]*W_dec[d,u]
// grid = 32 b x 8 d-chunks; each thread 4 u via float4; atomicAdd on top of
// the b_dec init done by prep.
// ---------------------------------------------------------------------------
__global__ __launch_bounds__(256) void dec_partial_kernel(
    const float* __restrict__ h_dec, const float* __restrict__ W_dec,
    float* __restrict__ dec_p)
{
    __shared__ float hs[128];
    const int b  = blockIdx.x >> 3;
    const int d0 = (blockIdx.x & 7) * 128;
    const int tid = threadIdx.x;
    const int u4 = tid * 4;
    if (tid < 128) hs[tid] = h_dec[b * Dz + d0 + tid];
    __syncthreads();
    float4 acc = {0.f, 0.f, 0.f, 0.f};
#pragma unroll 4
    for (int d = 0; d < 128; ++d) {
        const float  a = hs[d];
        const float4 w = *(const float4*)&W_dec[(size_t)(d0 + d) * Uz + u4];
        acc.x += a * w.x; acc.y += a * w.y; acc.z += a * w.z; acc.w += a * w.w;
    }
    float* o = dec_p + b * Uz + u4;
    atomicAdd(o + 0, acc.x); atomicAdd(o + 1, acc.y);
    atomicAdd(o + 2, acc.z); atomicAdd(o + 3, acc.w);
}

// ---------------------------------------------------------------------------
// K2 (hot, MFMA): 64x128 tile/block, BK=64, grid 1024 (4 blocks/CU).
// 4 waves, wave w = all 64 rows x n-groups {2w,2w+1}. Fragment-linear LDS,
// GLD16 staging, deferred tanh-reduction epilogue (once per block).
// ---------------------------------------------------------------------------
__global__ __launch_bounds__(256, 4) void score_mfma_kernel(
    const unsigned short* __restrict__ hbf,   // [Mz][Dz] bf16
    const unsigned short* __restrict__ wT,    // [Uz][Dz] bf16
    const float* __restrict__ dec_p,
    const float* __restrict__ W_com,
    const float* __restrict__ b_com,
    float* __restrict__ score)
{
    __shared__ unsigned short As[8 * 512];    // A units (mg,kg): mg<4, kg<2 -> 8 KB
    __shared__ unsigned short Bs[16 * 512];   // B units (ng,kg): ng<8, kg<2 -> 16 KB
    __shared__ float srow[64][4];

    const int tid  = threadIdx.x;
    const int w    = tid >> 6;
    const int lane = tid & 63;
    const int ln   = lane & 15;
    const int q    = lane >> 4;
    const int m0   = blockIdx.x * 64;         // 2048 % 64 == 0 -> single b
    const int b    = m0 / Sz;

    // A staging: wave w owns m-group w, both kg halves
    const unsigned short* a_src0 = hbf + (size_t)(m0 + w * 16 + ln) * Dz + q * 8;
    const unsigned short* a_src1 = a_src0 + 32;
    unsigned short* a_dst0 = As + (w * 2 + 0) * 512;
    unsigned short* a_dst1 = As + (w * 2 + 1) * 512;

    float racc[4][4];
#pragma unroll
    for (int i = 0; i < 4; ++i)
#pragma unroll
        for (int r = 0; r < 4; ++r) racc[i][r] = 0.f;

    for (int u0 = 0; u0 < Uz; u0 += 128) {
        f32x4 acc[4][2];
#pragma unroll
        for (int i = 0; i < 4; ++i)
#pragma unroll
            for (int j = 0; j < 2; ++j) acc[i][j] = (f32x4){0.f, 0.f, 0.f, 0.f};

        // B staging: wave w owns n-groups 2w, 2w+1, both kg halves
        const unsigned short* b_src0 = wT + (size_t)(u0 + (2 * w + 0) * 16 + ln) * Dz + q * 8;
        const unsigned short* b_src1 = b_src0 + 32;
        const unsigned short* b_src2 = wT + (size_t)(u0 + (2 * w + 1) * 16 + ln) * Dz + q * 8;
        const unsigned short* b_src3 = b_src2 + 32;
        unsigned short* b_dst0 = Bs + (4 * w + 0) * 512;
        unsigned short* b_dst1 = Bs + (4 * w + 1) * 512;
        unsigned short* b_dst2 = Bs + (4 * w + 2) * 512;
        unsigned short* b_dst3 = Bs + (4 * w + 3) * 512;

        for (int k0 = 0; k0 < Dz; k0 += 64) {
            __syncthreads();                  // protect LDS from prev readers
            GLD16(a_src0 + k0, a_dst0);
            GLD16(a_src1 + k0, a_dst1);
            GLD16(b_src0 + k0, b_dst0);
            GLD16(b_src1 + k0, b_dst1);
            GLD16(b_src2 + k0, b_dst2);
            GLD16(b_src3 + k0, b_dst3);
            __syncthreads();                  // vmcnt drained before barrier

#pragma unroll
            for (int kg = 0; kg < 2; ++kg) {
                bf16x8 af[4], bfr[2];
#pragma unroll
                for (int i = 0; i < 4; ++i)
                    af[i] = *(const bf16x8*)(As + (i * 2 + kg) * 512 + lane * 8);
#pragma unroll
                for (int j = 0; j < 2; ++j)
                    bfr[j] = *(const bf16x8*)(Bs + (4 * w + 2 * j + kg) * 512 + lane * 8);
#pragma unroll
                for (int i = 0; i < 4; ++i)
#pragma unroll
                    for (int j = 0; j < 2; ++j)
                        acc[i][j] = __builtin_amdgcn_mfma_f32_16x16x32_bf16(
                            af[i], bfr[j], acc[i][j], 0, 0, 0);
            }
        }

        // per-chunk: tanh + dot(W_com) accumulated into registers (no barrier)
        float dpv[2], wcv[2];
#pragma unroll
        for (int j = 0; j < 2; ++j) {
            const int u = u0 + (2 * w + j) * 16 + ln;
            dpv[j] = dec_p[b * Uz + u];
            wcv[j] = W_com[u];
        }
#pragma unroll
        for (int i = 0; i < 4; ++i)
#pragma unroll
            for (int r = 0; r < 4; ++r) {
                racc[i][r] += fast_tanh(acc[i][0][r] + dpv[0]) * wcv[0]
                            + fast_tanh(acc[i][1][r] + dpv[1]) * wcv[1];
            }
    }

    // one reduction at the end: sum over 16 ln-lanes (rows = i*16 + q*4 + r)
#pragma unroll
    for (int off = 1; off < 16; off <<= 1)
#pragma unroll
        for (int i = 0; i < 4; ++i)
#pragma unroll
            for (int r = 0; r < 4; ++r)
                racc[i][r] += __shfl_xor(racc[i][r], off, 64);
    if (ln == 0) {
#pragma unroll
        for (int i = 0; i < 4; ++i)
#pragma unroll
            for (int r = 0; r < 4; ++r)
                srow[i * 16 + q * 4 + r][w] = racc[i][r];
    }
    __syncthreads();
    if (tid < 64)
        score[m0 + tid] = srow[tid][0] + srow[tid][1] + srow[tid][2] + srow[tid][3] + b_com[0];
}

// ---------------------------------------------------------------------------
// softmax (blocks 0..31) + out_ctx init = b_enc (blocks 32..63)
// ---------------------------------------------------------------------------
__global__ __launch_bounds__(256) void softmax_init_kernel(
    const float* __restrict__ score, float* __restrict__ attn,
    const float* __restrict__ b_enc, float* __restrict__ out_ctx)
{
    __shared__ float red[256];
    const int tid = threadIdx.x;
    if (blockIdx.x >= Bz) {
        const int b2 = blockIdx.x - Bz;
        const int u4 = tid * 4;
        *(float4*)&out_ctx[b2 * Uz + u4] = *(const float4*)&b_enc[u4];
        return;
    }
    const int b = blockIdx.x;
    const float* srow = score + b * Sz;
    float v[8];
    float lm = -1e30f;
#pragma unroll
    for (int i = 0; i < 8; ++i) { v[i] = srow[i * 256 + tid]; lm = fmaxf(lm, v[i]); }
    red[tid] = lm; __syncthreads();
    for (int off = 128; off > 0; off >>= 1) {
        if (tid < off) red[tid] = fmaxf(red[tid], red[tid + off]);
        __syncthreads();
    }
    const float mx = red[0];
    __syncthreads();
    float ls = 0.f;
#pragma unroll
    for (int i = 0; i < 8; ++i) { v[i] = expf(v[i] - mx); ls += v[i]; }
    red[tid] = ls; __syncthreads();
    for (int off = 128; off > 0; off >>= 1) {
        if (tid < off) red[tid] += red[tid + off];
        __syncthreads();
    }
    const float inv = 1.f / red[0];
#pragma unroll
    for (int i = 0; i < 8; ++i) attn[b * Sz + i * 256 + tid] = v[i] * inv;
}

// ---------------------------------------------------------------------------
// wsum[b,d] = sum_s attn[b,s]*h_enc[b,s,d]; grid 1024 (64 s-rows per block)
// ---------------------------------------------------------------------------
__global__ __launch_bounds__(256) void wsum_kernel(
    const float* __restrict__ h_enc, const float* __restrict__ attn,
    float* __restrict__ wsum)
{
    __shared__ float aw[64];
    const int b  = blockIdx.x >> 5;
    const int s0 = (blockIdx.x & 31) * 64;
    const int tid = threadIdx.x;
    if (tid < 64) aw[tid] = attn[b * Sz + s0 + tid];
    __syncthreads();
    float4 acc = {0.f, 0.f, 0.f, 0.f};
    const float* base = h_enc + ((size_t)b * Sz + s0) * Dz + tid * 4;
#pragma unroll 4
    for (int s = 0; s < 64; ++s) {
        const float a = aw[s];
        const float4 h = *(const float4*)(base + (size_t)s * Dz);
        acc.x += a * h.x; acc.y += a * h.y; acc.z += a * h.z; acc.w += a * h.w;
    }
    float* o = wsum + b * Dz + tid * 4;
    atomicAdd(o + 0, acc.x); atomicAdd(o + 1, acc.y);
    atomicAdd(o + 2, acc.z); atomicAdd(o + 3, acc.w);
}

// ---------------------------------------------------------------------------
// out_ctx[b,u] += sum over d-chunk of wsum[b,d]*W_enc[d,u]
// grid = 32 b x 8 d-chunks; atomicAdd on top of b_enc init from softmax_init
// ---------------------------------------------------------------------------
__global__ __launch_bounds__(256) void ctx_partial_kernel(
    const float* __restrict__ wsum, const float* __restrict__ W_enc,
    float* __restrict__ out_ctx)
{
    __shared__ float hs[128];
    const int b  = blockIdx.x >> 3;
    const int d0 = (blockIdx.x & 7) * 128;
    const int tid = threadIdx.x;
    const int u4 = tid * 4;
    if (tid < 128) hs[tid] = wsum[b * Dz + d0 + tid];
    __syncthreads();
    float4 acc = {0.f, 0.f, 0.f, 0.f};
#pragma unroll 4
    for (int d = 0; d < 128; ++d) {
        const float  a = hs[d];
        const float4 wv = *(const float4*)&W_enc[(size_t)(d0 + d) * Uz + u4];
        acc.x += a * wv.x; acc.y += a * wv.y; acc.z += a * wv.z; acc.w += a * wv.w;
    }
    float* o = out_ctx + b * Uz + u4;
    atomicAdd(o + 0, acc.x); atomicAdd(o + 1, acc.y);
    atomicAdd(o + 2, acc.z); atomicAdd(o + 3, acc.w);
}

// ---------------------------------------------------------------------------
// Fallback fp32 path (only if ws too small for bf16 staging)
// ---------------------------------------------------------------------------
__global__ __launch_bounds__(256) void dec_proj_kernel(
    const float* __restrict__ h_dec, const float* __restrict__ W_dec,
    const float* __restrict__ b_dec, float* __restrict__ dec_p)
{
    __shared__ float hs[Dz];
    const int b = blockIdx.x >> 2;
    const int u = ((blockIdx.x & 3) << 8) + threadIdx.x;
    for (int d = threadIdx.x; d < Dz; d += 256) hs[d] = h_dec[b * Dz + d];
    __syncthreads();
    float acc = 0.f;
#pragma unroll 4
    for (int d = 0; d < Dz; ++d) acc += hs[d] * W_dec[d * Uz + u];
    dec_p[b * Uz + u] = acc + b_dec[u];
}

#define MT 64
#define NT 64
#define KT 64
__global__ __launch_bounds__(256) void score_kernel(
    const float* __restrict__ h_enc, const float* __restrict__ W_enc,
    const float* __restrict__ dec_p, const float* __restrict__ W_com,
    const float* __restrict__ b_com, float* __restrict__ score)
{
    __shared__ __align__(16) float As[KT][MT + 4];
    __shared__ __align__(16) float Bs[KT][NT + 4];
    __shared__ float red[MT][17];
    const int tid = threadIdx.x;
    const int tx = tid & 15;
    const int ty = tid >> 4;
    const int m0 = blockIdx.x * MT;
    const int b  = m0 / Sz;
    float s_acc = 0.f;
    for (int u0 = 0; u0 < Uz; u0 += NT) {
        float acc[4][4];
#pragma unroll
        for (int i = 0; i < 4; ++i)
#pragma unroll
            for (int j = 0; j < 4; ++j) acc[i][j] = 0.f;
        for (int k0 = 0; k0 < Dz; k0 += KT) {
            __syncthreads();
#pragma unroll
            for (int i = 0; i < 4; ++i) {
                const int row = ty + i * 16;
                const int c4  = tx * 4;
                const float4 v = *(const float4*)&h_enc[(size_t)(m0 + row) * Dz + k0 + c4];
                As[c4 + 0][row] = v.x; As[c4 + 1][row] = v.y;
                As[c4 + 2][row] = v.z; As[c4 + 3][row] = v.w;
            }
#pragma unroll
            for (int i = 0; i < 4; ++i) {
                const int row = ty + i * 16;
                *(float4*)&Bs[row][tx * 4] =
                    *(const float4*)&W_enc[(size_t)(k0 + row) * Uz + u0 + tx * 4];
            }
            __syncthreads();
#pragma unroll 8
            for (int k = 0; k < KT; ++k) {
                const float4 a = *(const float4*)&As[k][ty * 4];
                const float4 wv = *(const float4*)&Bs[k][tx * 4];
                acc[0][0] += a.x * wv.x; acc[0][1] += a.x * wv.y; acc[0][2] += a.x * wv.z; acc[0][3] += a.x * wv.w;
                acc[1][0] += a.y * wv.x; acc[1][1] += a.y * wv.y; acc[1][2] += a.y * wv.z; acc[1][3] += a.y * wv.w;
                acc[2][0] += a.z * wv.x; acc[2][1] += a.z * wv.y; acc[2][2] += a.z * wv.z; acc[2][3] += a.z * wv.w;
                acc[3][0] += a.w * wv.x; acc[3][1] += a.w * wv.y; acc[3][2] += a.w * wv.z; acc[3][3] += a.w * wv.w;
            }
        }
        const float4 dp = *(const float4*)&dec_p[b * Uz + u0 + tx * 4];
        const float4 wc = *(const float4*)&W_com[u0 + tx * 4];
#pragma unroll
        for (int i = 0; i < 4; ++i) {
            const float p = tanhf(acc[i][0] + dp.x) * wc.x + tanhf(acc[i][1] + dp.y) * wc.y
                          + tanhf(acc[i][2] + dp.z) * wc.z + tanhf(acc[i][3] + dp.w) * wc.w;
            red[ty * 4 + i][tx] = p;
        }
        __syncthreads();
        if (tid < MT) {
            float t = 0.f;
#pragma unroll
            for (int j = 0; j < 16; ++j) t += red[tid][j];
            s_acc += t;
        }
    }
    if (tid < MT) score[m0 + tid] = s_acc + b_com[0];
}

__global__ __launch_bounds__(256) void ctx_kernel(
    const float* __restrict__ wsum, const float* __restrict__ W_enc,
    const float* __restrict__ b_enc, float* __restrict__ out)
{
    __shared__ float hs[Dz];
    const int b = blockIdx.x >> 2;
    const int u = ((blockIdx.x & 3) << 8) + threadIdx.x;
    for (int d = threadIdx.x; d < Dz; d += 256) hs[d] = wsum[b * Dz + d];
    __syncthreads();
    float acc = 0.f;
#pragma unroll 4
    for (int d = 0; d < Dz; ++d) acc += hs[d] * W_enc[d * Uz + u];
    out[b * Uz + u] = acc + b_enc[u];
}

// ---------------------------------------------------------------------------
extern "C" void kernel_launch(void* const* d_in, const int* in_sizes, int n_in,
                              void* d_out, int out_size, void* d_ws, size_t ws_size,
                              hipStream_t stream)
{
    const float* h_enc = (const float*)d_in[0];
    const float* h_dec = (const float*)d_in[1];
    const float* W_enc = (const float*)d_in[2];
    const float* b_enc = (const float*)d_in[3];
    const float* W_dec = (const float*)d_in[4];
    const float* b_dec = (const float*)d_in[5];
    const float* W_com = (const float*)d_in[6];
    const float* b_com = (const float*)d_in[7];

    float* out_ctx  = (float*)d_out;            // [B,U]
    float* out_attn = out_ctx + Bz * Uz;        // [B,S]

    const size_t HBF_BYTES = (size_t)Mz * Dz * 2;       // 128 MiB
    const size_t WT_BYTES  = (size_t)Uz * Dz * 2;       // 2 MiB
    const size_t SMALL     = (size_t)(Bz*Uz + Bz*Sz + Bz*Dz) * 4;
    const size_t need      = HBF_BYTES + WT_BYTES + SMALL;

    if (ws_size >= need) {
        char* wsb = (char*)d_ws;
        unsigned short* hbf = (unsigned short*)wsb;
        unsigned short* wT  = (unsigned short*)(wsb + HBF_BYTES);
        float* dec_p = (float*)(wsb + HBF_BYTES + WT_BYTES);
        float* score = dec_p + Bz * Uz;
        float* wsum  = score + Bz * Sz;

        prep_kernel<<<CONV_BLOCKS + WT_BLOCKS + DECI_BLOCKS, 256, 0, stream>>>(
            h_enc, hbf, W_enc, wT, b_dec, dec_p);
        dec_partial_kernel<<<Bz * 8, 256, 0, stream>>>(h_dec, W_dec, dec_p);
        score_mfma_kernel<<<Mz / 64, 256, 0, stream>>>(hbf, wT, dec_p, W_com, b_com, score);
        softmax_init_kernel<<<2 * Bz, 256, 0, stream>>>(score, out_attn, b_enc, out_ctx);
        hipMemsetAsync(wsum, 0, Bz * Dz * sizeof(float), stream);
        wsum_kernel<<<Bz * 32, 256, 0, stream>>>(h_enc, out_attn, wsum);
        ctx_partial_kernel<<<Bz * 8, 256, 0, stream>>>(wsum, W_enc, out_ctx);
    } else {
        float* ws    = (float*)d_ws;
        float* dec_p = ws;
        float* score = ws + Bz * Uz;
        float* wsum  = ws + Bz * Uz + Bz * Sz;

        dec_proj_kernel<<<(Bz * Uz) / 256, 256, 0, stream>>>(h_dec, W_dec, b_dec, dec_p);
        score_kernel<<<Mz / MT, 256, 0, stream>>>(h_enc, W_enc, dec_p, W_com, b_com, score);
        softmax_init_kernel<<<2 * Bz, 256, 0, stream>>>(score, out_attn, b_enc, out_ctx);
        hipMemsetAsync(wsum, 0, Bz * Dz * sizeof(float), stream);
        wsum_kernel<<<Bz * 32, 256, 0, stream>>>(h_enc, out_attn, wsum);
        ctx_kernel<<<(Bz * Uz) / 256, 256, 0, stream>>>(wsum, W_enc, b_enc, out_ctx);
    }
}

// Round 4
// 763.766 us; speedup vs baseline: 3.7538x; 1.1301x over previous
//
#include <hip/hip_runtime.h>
#include <math.h>
#include <stdint.h>

#define Bz 32
#define Sz 2048
#define Dz 1024
#define Uz 1024
#define Mz (Bz*Sz)

typedef __attribute__((ext_vector_type(8))) short bf16x8;
typedef __attribute__((ext_vector_type(4))) float f32x4;

__device__ __forceinline__ unsigned short f2bf(float f) {
    union { float f; uint32_t u; } v; v.f = f;
    uint32_t r = v.u + 0x7FFFu + ((v.u >> 16) & 1u);   // RNE
    return (unsigned short)(r >> 16);
}

__device__ __forceinline__ float fast_tanh(float x) {
    float e = __expf(2.f * x);
    return 1.f - 2.f * __builtin_amdgcn_rcpf(e + 1.f);
}

#define GLD16(gsrc, ldst) \
    __builtin_amdgcn_global_load_lds((__attribute__((address_space(1))) void*)(void*)(gsrc), \
        (__attribute__((address_space(3))) void*)(ldst), 16, 0, 0)

#define CONV_BLOCKS 16384   // (Mz*Dz)/(256*16)
#define WT_BLOCKS   256
#define DECI_BLOCKS 32
#define SINIT_BLOCKS 64     // Bz*Sz / (256*4)

// ---------------------------------------------------------------------------
// PREP (fused): h_enc->bf16 | W_enc->wT bf16 | dec_p = b_dec | score = b_com
// ---------------------------------------------------------------------------
__global__ __launch_bounds__(256) void prep_kernel(
    const float* __restrict__ h_enc, unsigned short* __restrict__ hbf,
    const float* __restrict__ W_enc, unsigned short* __restrict__ wT,
    const float* __restrict__ b_dec, float* __restrict__ dec_p,
    const float* __restrict__ b_com, float* __restrict__ score)
{
    __shared__ float tile[64][65];
    const int bid = blockIdx.x;
    const int tid = threadIdx.x;
    if (bid < CONV_BLOCKS) {
        const size_t i = ((size_t)bid * 256 + tid) * 16;
#pragma unroll
        for (int h = 0; h < 2; ++h) {
            const float4 a = *(const float4*)(h_enc + i + h * 8);
            const float4 c = *(const float4*)(h_enc + i + h * 8 + 4);
            union { unsigned short s[8]; uint4 v; } o;
            o.s[0] = f2bf(a.x); o.s[1] = f2bf(a.y); o.s[2] = f2bf(a.z); o.s[3] = f2bf(a.w);
            o.s[4] = f2bf(c.x); o.s[5] = f2bf(c.y); o.s[6] = f2bf(c.z); o.s[7] = f2bf(c.w);
            *(uint4*)(hbf + i + h * 8) = o.v;
        }
    } else if (bid < CONV_BLOCKS + WT_BLOCKS) {
        const int b2 = bid - CONV_BLOCKS;
        const int c  = tid & 63;
        const int r0 = tid >> 6;
        const int u0 = (b2 & 15) * 64;
        const int d0 = (b2 >> 4) * 64;
        for (int r = r0; r < 64; r += 4)
            tile[r][c] = W_enc[(size_t)(d0 + r) * Uz + u0 + c];
        __syncthreads();
        for (int r = r0; r < 64; r += 4)
            wT[(size_t)(u0 + r) * Dz + d0 + c] = f2bf(tile[c][r]);
    } else if (bid < CONV_BLOCKS + WT_BLOCKS + DECI_BLOCKS) {
        const int b3 = bid - (CONV_BLOCKS + WT_BLOCKS);
        const int u4 = tid * 4;
        *(float4*)&dec_p[b3 * Uz + u4] = *(const float4*)&b_dec[u4];
    } else {
        const int b4 = bid - (CONV_BLOCKS + WT_BLOCKS + DECI_BLOCKS);
        const float bc = b_com[0];
        const int i4 = (b4 * 256 + tid) * 4;
        float4 v = {bc, bc, bc, bc};
        *(float4*)&score[i4] = v;
    }
}

// ---------------------------------------------------------------------------
// dec_p[b,u] += partial h_dec[b,:]@W_dec (8 d-chunks, atop b_dec init)
// ---------------------------------------------------------------------------
__global__ __launch_bounds__(256) void dec_partial_kernel(
    const float* __restrict__ h_dec, const float* __restrict__ W_dec,
    float* __restrict__ dec_p)
{
    __shared__ float hs[128];
    const int b  = blockIdx.x >> 3;
    const int d0 = (blockIdx.x & 7) * 128;
    const int tid = threadIdx.x;
    const int u4 = tid * 4;
    if (tid < 128) hs[tid] = h_dec[b * Dz + d0 + tid];
    __syncthreads();
    float4 acc = {0.f, 0.f, 0.f, 0.f};
#pragma unroll 4
    for (int d = 0; d < 128; ++d) {
        const float  a = hs[d];
        const float4 w = *(const float4*)&W_dec[(size_t)(d0 + d) * Uz + u4];
        acc.x += a * w.x; acc.y += a * w.y; acc.z += a * w.z; acc.w += a * w.w;
    }
    float* o = dec_p + b * Uz + u4;
    atomicAdd(o + 0, acc.x); atomicAdd(o + 1, acc.y);
    atomicAdd(o + 2, acc.z); atomicAdd(o + 3, acc.w);
}

// ---------------------------------------------------------------------------
// K2 (hot, MFMA): 128x128 tile, BK=32, U split across 2 blocks (grid 1024).
// 4 waves in 2x2 grid, each wave 4x4 frags of 16x16x32 bf16 MFMA.
// Fragment-linear LDS + GLD16 (4/wave/kstep). Deferred register epilogue:
// tanh+W_com accumulated per chunk in racc, one shfl-reduce + atomicAdd at
// the end (score pre-initialized to b_com by prep).
// ---------------------------------------------------------------------------
__global__ __launch_bounds__(256) void score_mfma_kernel(
    const unsigned short* __restrict__ hbf,   // [Mz][Dz] bf16
    const unsigned short* __restrict__ wT,    // [Uz][Dz] bf16
    const float* __restrict__ dec_p,
    const float* __restrict__ W_com,
    float* __restrict__ score)
{
    __shared__ unsigned short As[8 * 512];    // 8 m-groups x 64 lanes x 8 bf16
    __shared__ unsigned short Bs[8 * 512];    // 8 n-groups

    const int tid  = threadIdx.x;
    const int w    = tid >> 6;
    const int lane = tid & 63;
    const int ln   = lane & 15;
    const int q    = lane >> 4;
    const int wm   = w & 1;
    const int wn   = w >> 1;
    const int m0   = (blockIdx.x >> 1) * 128;  // 512 m-blocks
    const int uh   = blockIdx.x & 1;           // u-half: [uh*512, uh*512+512)
    const int b    = m0 / Sz;
    const int ub   = uh * 512;

    const int g0 = 2 * w;                      // staging: wave w owns units g0,g0+1
    const unsigned short* a_src0 = hbf + (size_t)(m0 + g0 * 16 + ln) * Dz + q * 8;
    const unsigned short* a_src1 = a_src0 + (size_t)16 * Dz;
    unsigned short* a_dst0 = As + g0 * 512;
    unsigned short* a_dst1 = a_dst0 + 512;

    float racc[4][4];
#pragma unroll
    for (int i = 0; i < 4; ++i)
#pragma unroll
        for (int r = 0; r < 4; ++r) racc[i][r] = 0.f;

    for (int u0 = 0; u0 < 512; u0 += 128) {
        f32x4 acc[4][4];
#pragma unroll
        for (int i = 0; i < 4; ++i)
#pragma unroll
            for (int j = 0; j < 4; ++j) acc[i][j] = (f32x4){0.f, 0.f, 0.f, 0.f};

        const unsigned short* b_src0 = wT + (size_t)(ub + u0 + g0 * 16 + ln) * Dz + q * 8;
        const unsigned short* b_src1 = b_src0 + (size_t)16 * Dz;
        unsigned short* b_dst0 = Bs + g0 * 512;
        unsigned short* b_dst1 = b_dst0 + 512;

        for (int k0 = 0; k0 < Dz; k0 += 32) {
            __syncthreads();                  // protect LDS from prev readers
            GLD16(a_src0 + k0, a_dst0);
            GLD16(a_src1 + k0, a_dst1);
            GLD16(b_src0 + k0, b_dst0);
            GLD16(b_src1 + k0, b_dst1);
            __syncthreads();                  // vmcnt drained before barrier

            bf16x8 af[4], bfr[4];
#pragma unroll
            for (int i = 0; i < 4; ++i)
                af[i] = *(const bf16x8*)(As + (wm * 4 + i) * 512 + lane * 8);
#pragma unroll
            for (int j = 0; j < 4; ++j)
                bfr[j] = *(const bf16x8*)(Bs + (wn * 4 + j) * 512 + lane * 8);
#pragma unroll
            for (int i = 0; i < 4; ++i)
#pragma unroll
                for (int j = 0; j < 4; ++j)
                    acc[i][j] = __builtin_amdgcn_mfma_f32_16x16x32_bf16(
                        af[i], bfr[j], acc[i][j], 0, 0, 0);
        }

        // per-chunk: tanh + dot(W_com) into registers — no barrier, no LDS
        float dpv[4], wcv[4];
#pragma unroll
        for (int j = 0; j < 4; ++j) {
            const int u = ub + u0 + (wn * 4 + j) * 16 + ln;
            dpv[j] = dec_p[b * Uz + u];
            wcv[j] = W_com[u];
        }
#pragma unroll
        for (int i = 0; i < 4; ++i)
#pragma unroll
            for (int r = 0; r < 4; ++r) {
                float v = 0.f;
#pragma unroll
                for (int j = 0; j < 4; ++j)
                    v += fast_tanh(acc[i][j][r] + dpv[j]) * wcv[j];
                racc[i][r] += v;
            }
    }

    // single reduction: sum over the 16 ln-lanes, then atomicAdd partials
#pragma unroll
    for (int off = 1; off < 16; off <<= 1)
#pragma unroll
        for (int i = 0; i < 4; ++i)
#pragma unroll
            for (int r = 0; r < 4; ++r)
                racc[i][r] += __shfl_xor(racc[i][r], off, 64);
    if (ln == 0) {
#pragma unroll
        for (int i = 0; i < 4; ++i)
#pragma unroll
            for (int r = 0; r < 4; ++r)
                atomicAdd(&score[m0 + wm * 64 + i * 16 + q * 4 + r], racc[i][r]);
    }
}

// ---------------------------------------------------------------------------
// softmax (blocks 0..31) + out_ctx init = b_enc (32..63) + wsum zero (64..95)
// ---------------------------------------------------------------------------
__global__ __launch_bounds__(256) void softmax_init_kernel(
    const float* __restrict__ score, float* __restrict__ attn,
    const float* __restrict__ b_enc, float* __restrict__ out_ctx,
    float* __restrict__ wsum)
{
    __shared__ float red[256];
    const int tid = threadIdx.x;
    if (blockIdx.x >= 2 * Bz) {
        const int b3 = blockIdx.x - 2 * Bz;
        float4 z = {0.f, 0.f, 0.f, 0.f};
        *(float4*)&wsum[b3 * Dz + tid * 4] = z;
        return;
    }
    if (blockIdx.x >= Bz) {
        const int b2 = blockIdx.x - Bz;
        const int u4 = tid * 4;
        *(float4*)&out_ctx[b2 * Uz + u4] = *(const float4*)&b_enc[u4];
        return;
    }
    const int b = blockIdx.x;
    const float* srow = score + b * Sz;
    float v[8];
    float lm = -1e30f;
#pragma unroll
    for (int i = 0; i < 8; ++i) { v[i] = srow[i * 256 + tid]; lm = fmaxf(lm, v[i]); }
    red[tid] = lm; __syncthreads();
    for (int off = 128; off > 0; off >>= 1) {
        if (tid < off) red[tid] = fmaxf(red[tid], red[tid + off]);
        __syncthreads();
    }
    const float mx = red[0];
    __syncthreads();
    float ls = 0.f;
#pragma unroll
    for (int i = 0; i < 8; ++i) { v[i] = expf(v[i] - mx); ls += v[i]; }
    red[tid] = ls; __syncthreads();
    for (int off = 128; off > 0; off >>= 1) {
        if (tid < off) red[tid] += red[tid + off];
        __syncthreads();
    }
    const float inv = 1.f / red[0];
#pragma unroll
    for (int i = 0; i < 8; ++i) attn[b * Sz + i * 256 + tid] = v[i] * inv;
}

// ---------------------------------------------------------------------------
// wsum[b,d] = sum_s attn[b,s]*h_enc[b,s,d]; grid 1024 (64 s-rows per block)
// ---------------------------------------------------------------------------
__global__ __launch_bounds__(256) void wsum_kernel(
    const float* __restrict__ h_enc, const float* __restrict__ attn,
    float* __restrict__ wsum)
{
    __shared__ float aw[64];
    const int b  = blockIdx.x >> 5;
    const int s0 = (blockIdx.x & 31) * 64;
    const int tid = threadIdx.x;
    if (tid < 64) aw[tid] = attn[b * Sz + s0 + tid];
    __syncthreads();
    float4 acc = {0.f, 0.f, 0.f, 0.f};
    const float* base = h_enc + ((size_t)b * Sz + s0) * Dz + tid * 4;
#pragma unroll 4
    for (int s = 0; s < 64; ++s) {
        const float a = aw[s];
        const float4 h = *(const float4*)(base + (size_t)s * Dz);
        acc.x += a * h.x; acc.y += a * h.y; acc.z += a * h.z; acc.w += a * h.w;
    }
    float* o = wsum + b * Dz + tid * 4;
    atomicAdd(o + 0, acc.x); atomicAdd(o + 1, acc.y);
    atomicAdd(o + 2, acc.z); atomicAdd(o + 3, acc.w);
}

// ---------------------------------------------------------------------------
// out_ctx[b,u] += partial wsum[b,:]@W_enc (8 d-chunks, atop b_enc init)
// ---------------------------------------------------------------------------
__global__ __launch_bounds__(256) void ctx_partial_kernel(
    const float* __restrict__ wsum, const float* __restrict__ W_enc,
    float* __restrict__ out_ctx)
{
    __shared__ float hs[128];
    const int b  = blockIdx.x >> 3;
    const int d0 = (blockIdx.x & 7) * 128;
    const int tid = threadIdx.x;
    const int u4 = tid * 4;
    if (tid < 128) hs[tid] = wsum[b * Dz + d0 + tid];
    __syncthreads();
    float4 acc = {0.f, 0.f, 0.f, 0.f};
#pragma unroll 4
    for (int d = 0; d < 128; ++d) {
        const float  a = hs[d];
        const float4 wv = *(const float4*)&W_enc[(size_t)(d0 + d) * Uz + u4];
        acc.x += a * wv.x; acc.y += a * wv.y; acc.z += a * wv.z; acc.w += a * wv.w;
    }
    float* o = out_ctx + b * Uz + u4;
    atomicAdd(o + 0, acc.x); atomicAdd(o + 1, acc.y);
    atomicAdd(o + 2, acc.z); atomicAdd(o + 3, acc.w);
}

// ---------------------------------------------------------------------------
// Fallback fp32 path (only if ws too small for bf16 staging)
// ---------------------------------------------------------------------------
__global__ __launch_bounds__(256) void dec_proj_kernel(
    const float* __restrict__ h_dec, const float* __restrict__ W_dec,
    const float* __restrict__ b_dec, float* __restrict__ dec_p)
{
    __shared__ float hs[Dz];
    const int b = blockIdx.x >> 2;
    const int u = ((blockIdx.x & 3) << 8) + threadIdx.x;
    for (int d = threadIdx.x; d < Dz; d += 256) hs[d] = h_dec[b * Dz + d];
    __syncthreads();
    float acc = 0.f;
#pragma unroll 4
    for (int d = 0; d < Dz; ++d) acc += hs[d] * W_dec[d * Uz + u];
    dec_p[b * Uz + u] = acc + b_dec[u];
}

#define MT 64
#define NT 64
#define KT 64
__global__ __launch_bounds__(256) void score_kernel(
    const float* __restrict__ h_enc, const float* __restrict__ W_enc,
    const float* __restrict__ dec_p, const float* __restrict__ W_com,
    const float* __restrict__ b_com, float* __restrict__ score)
{
    __shared__ __align__(16) float As[KT][MT + 4];
    __shared__ __align__(16) float Bs[KT][NT + 4];
    __shared__ float red[MT][17];
    const int tid = threadIdx.x;
    const int tx = tid & 15;
    const int ty = tid >> 4;
    const int m0 = blockIdx.x * MT;
    const int b  = m0 / Sz;
    float s_acc = 0.f;
    for (int u0 = 0; u0 < Uz; u0 += NT) {
        float acc[4][4];
#pragma unroll
        for (int i = 0; i < 4; ++i)
#pragma unroll
            for (int j = 0; j < 4; ++j) acc[i][j] = 0.f;
        for (int k0 = 0; k0 < Dz; k0 += KT) {
            __syncthreads();
#pragma unroll
            for (int i = 0; i < 4; ++i) {
                const int row = ty + i * 16;
                const int c4  = tx * 4;
                const float4 v = *(const float4*)&h_enc[(size_t)(m0 + row) * Dz + k0 + c4];
                As[c4 + 0][row] = v.x; As[c4 + 1][row] = v.y;
                As[c4 + 2][row] = v.z; As[c4 + 3][row] = v.w;
            }
#pragma unroll
            for (int i = 0; i < 4; ++i) {
                const int row = ty + i * 16;
                *(float4*)&Bs[row][tx * 4] =
                    *(const float4*)&W_enc[(size_t)(k0 + row) * Uz + u0 + tx * 4];
            }
            __syncthreads();
#pragma unroll 8
            for (int k = 0; k < KT; ++k) {
                const float4 a = *(const float4*)&As[k][ty * 4];
                const float4 wv = *(const float4*)&Bs[k][tx * 4];
                acc[0][0] += a.x * wv.x; acc[0][1] += a.x * wv.y; acc[0][2] += a.x * wv.z; acc[0][3] += a.x * wv.w;
                acc[1][0] += a.y * wv.x; acc[1][1] += a.y * wv.y; acc[1][2] += a.y * wv.z; acc[1][3] += a.y * wv.w;
                acc[2][0] += a.z * wv.x; acc[2][1] += a.z * wv.y; acc[2][2] += a.z * wv.z; acc[2][3] += a.z * wv.w;
                acc[3][0] += a.w * wv.x; acc[3][1] += a.w * wv.y; acc[3][2] += a.w * wv.z; acc[3][3] += a.w * wv.w;
            }
        }
        const float4 dp = *(const float4*)&dec_p[b * Uz + u0 + tx * 4];
        const float4 wc = *(const float4*)&W_com[u0 + tx * 4];
#pragma unroll
        for (int i = 0; i < 4; ++i) {
            const float p = tanhf(acc[i][0] + dp.x) * wc.x + tanhf(acc[i][1] + dp.y) * wc.y
                          + tanhf(acc[i][2] + dp.z) * wc.z + tanhf(acc[i][3] + dp.w) * wc.w;
            red[ty * 4 + i][tx] = p;
        }
        __syncthreads();
        if (tid < MT) {
            float t = 0.f;
#pragma unroll
            for (int j = 0; j < 16; ++j) t += red[tid][j];
            s_acc += t;
        }
    }
    if (tid < MT) score[m0 + tid] = s_acc + b_com[0];
}

__global__ __launch_bounds__(256) void ctx_kernel(
    const float* __restrict__ wsum, const float* __restrict__ W_enc,
    const float* __restrict__ b_enc, float* __restrict__ out)
{
    __shared__ float hs[Dz];
    const int b = blockIdx.x >> 2;
    const int u = ((blockIdx.x & 3) << 8) + threadIdx.x;
    for (int d = threadIdx.x; d < Dz; d += 256) hs[d] = wsum[b * Dz + d];
    __syncthreads();
    float acc = 0.f;
#pragma unroll 4
    for (int d = 0; d < Dz; ++d) acc += hs[d] * W_enc[d * Uz + u];
    out[b * Uz + u] = acc + b_enc[u];
}

// ---------------------------------------------------------------------------
extern "C" void kernel_launch(void* const* d_in, const int* in_sizes, int n_in,
                              void* d_out, int out_size, void* d_ws, size_t ws_size,
                              hipStream_t stream)
{
    const float* h_enc = (const float*)d_in[0];
    const float* h_dec = (const float*)d_in[1];
    const float* W_enc = (const float*)d_in[2];
    const float* b_enc = (const float*)d_in[3];
    const float* W_dec = (const float*)d_in[4];
    const float* b_dec = (const float*)d_in[5];
    const float* W_com = (const float*)d_in[6];
    const float* b_com = (const float*)d_in[7];

    float* out_ctx  = (float*)d_out;            // [B,U]
    float* out_attn = out_ctx + Bz * Uz;        // [B,S]

    const size_t HBF_BYTES = (size_t)Mz * Dz * 2;       // 128 MiB
    const size_t WT_BYTES  = (size_t)Uz * Dz * 2;       // 2 MiB
    const size_t SMALL     = (size_t)(Bz*Uz + Bz*Sz + Bz*Dz) * 4;
    const size_t need      = HBF_BYTES + WT_BYTES + SMALL;

    if (ws_size >= need) {
        char* wsb = (char*)d_ws;
        unsigned short* hbf = (unsigned short*)wsb;
        unsigned short* wT  = (unsigned short*)(wsb + HBF_BYTES);
        float* dec_p = (float*)(wsb + HBF_BYTES + WT_BYTES);
        float* score = dec_p + Bz * Uz;
        float* wsum  = score + Bz * Sz;

        prep_kernel<<<CONV_BLOCKS + WT_BLOCKS + DECI_BLOCKS + SINIT_BLOCKS, 256, 0, stream>>>(
            h_enc, hbf, W_enc, wT, b_dec, dec_p, b_com, score);
        dec_partial_kernel<<<Bz * 8, 256, 0, stream>>>(h_dec, W_dec, dec_p);
        score_mfma_kernel<<<(Mz / 128) * 2, 256, 0, stream>>>(hbf, wT, dec_p, W_com, score);
        softmax_init_kernel<<<3 * Bz, 256, 0, stream>>>(score, out_attn, b_enc, out_ctx, wsum);
        wsum_kernel<<<Bz * 32, 256, 0, stream>>>(h_enc, out_attn, wsum);
        ctx_partial_kernel<<<Bz * 8, 256, 0, stream>>>(wsum, W_enc, out_ctx);
    } else {
        float* ws    = (float*)d_ws;
        float* dec_p = ws;
        float* score = ws + Bz * Uz;
        float* wsum  = ws + Bz * Uz + Bz * Sz;

        dec_proj_kernel<<<(Bz * Uz) / 256, 256, 0, stream>>>(h_dec, W_dec, b_dec, dec_p);
        score_kernel<<<Mz / MT, 256, 0, stream>>>(h_enc, W_enc, dec_p, W_com, b_com, score);
        softmax_init_kernel<<<3 * Bz, 256, 0, stream>>>(score, out_attn, b_enc, out_ctx, wsum);
        wsum_kernel<<<Bz * 32, 256, 0, stream>>>(h_enc, out_attn, wsum);
        ctx_kernel<<<(Bz * Uz) / 256, 256, 0, stream>>>(wsum, W_enc, b_enc, out_ctx);
    }
}